// Round 10
// baseline (71.508 us; speedup 1.0000x reference)
//
#include <hip/hip_runtime.h>
#include <hip/hip_bf16.h>
#include <math.h>

#define BB 8
#define FF 16
#define DD 256
#define HH 64
#define WW 64

typedef short bf16x8 __attribute__((ext_vector_type(8)));
typedef float f32x4 __attribute__((ext_vector_type(4)));

__device__ inline ushort f2bf(float f) {
    union { float f; unsigned u; } v; v.f = f;
    unsigned r = v.u + 0x7FFFu + ((v.u >> 16) & 1u);   // RNE
    return (ushort)(r >> 16);
}

// ---------------------------------------------------------------------------
// Kernel A: fused cast_x (blocks 0..511) + prep_filter (blocks 512..767).
// Both are memory-bound on disjoint streams; fusing overlaps them.
// ---------------------------------------------------------------------------
__global__ __launch_bounds__(256) void prep_fused(
    const float* __restrict__ x,              // (B, D, 64, 64)
    const float* __restrict__ bank_request,   // (B, F)
    const float* __restrict__ style,          // (B, 1, D, 1, 1)
    const float* __restrict__ bank_weight,    // (F, D, D, 3, 3)
    ushort* __restrict__ xb,                  // (B, 64, 64, D)
    ushort* __restrict__ Ak)                  // (B, 9, 32, 256, 8)
{
    __shared__ ushort ls[64][258];
    __shared__ float wsm[BB][FF];
    __shared__ float red[4][BB];
    __shared__ float nrm[BB];

    const int t = threadIdx.x;

    if (blockIdx.x < 512) {
        // ----- cast_x: fp32 -> bf16 transpose to xb[b][r][c][i] -----
        const int r = blockIdx.x & 63, b = blockIdx.x >> 6;

        const int c4 = (t & 15) * 4;
        const int ig = t >> 4;
#pragma unroll
        for (int j = 0; j < 16; ++j) {
            const int i = ig * 16 + j;
            const float4 xv = *reinterpret_cast<const float4*>(
                x + (((size_t)(b * DD + i) * HH) + r) * WW + c4);
            ls[c4 + 0][i] = f2bf(xv.x);
            ls[c4 + 1][i] = f2bf(xv.y);
            ls[c4 + 2][i] = f2bf(xv.z);
            ls[c4 + 3][i] = f2bf(xv.w);
        }
        __syncthreads();

        const int i2 = t & 127;
        const int ch = t >> 7;
#pragma unroll
        for (int cl = 0; cl < 32; ++cl) {
            const int c = ch * 32 + cl;
            const unsigned u = (unsigned)ls[c][2 * i2] | ((unsigned)ls[c][2 * i2 + 1] << 16);
            *reinterpret_cast<unsigned*>(xb + (((size_t)(b * HH + r) * WW) + c) * DD + 2 * i2) = u;
        }
        return;
    }

    // ----- prep_filter: all batches, one pass over bank_weight -----
    const int o = blockIdx.x - 512;
    const int i = t;

    if (i < BB) {
        float v[FF];
        float m = -1e30f;
#pragma unroll
        for (int f = 0; f < FF; ++f) {
            v[f] = bank_request[i * FF + f];
            m = fmaxf(m, v[f]);
        }
        float s = 0.f;
#pragma unroll
        for (int f = 0; f < FF; ++f) { v[f] = __expf(v[f] - m); s += v[f]; }
        const float inv = 1.0f / s;
#pragma unroll
        for (int f = 0; f < FF; ++f) wsm[i][f] = v[f] * inv;
    }
    __syncthreads();

    float acc9[BB][9];
#pragma unroll
    for (int b = 0; b < BB; ++b)
#pragma unroll
        for (int j = 0; j < 9; ++j) acc9[b][j] = 0.f;

    float pre[2][9];
#pragma unroll
    for (int s = 0; s < 2; ++s) {
        const float* p = bank_weight + ((size_t)(s * DD + o) * DD + i) * 9;
#pragma unroll
        for (int j = 0; j < 9; ++j) pre[s][j] = p[j];
    }
#pragma unroll
    for (int f = 0; f < FF; ++f) {
        const int sl = f & 1;
        float cur[9];
#pragma unroll
        for (int j = 0; j < 9; ++j) cur[j] = pre[sl][j];
        if (f + 2 < FF) {
            const float* p = bank_weight + ((size_t)((f + 2) * DD + o) * DD + i) * 9;
#pragma unroll
            for (int j = 0; j < 9; ++j) pre[sl][j] = p[j];
        }
#pragma unroll
        for (int b = 0; b < BB; ++b) {
            const float wf = wsm[b][f];
#pragma unroll
            for (int j = 0; j < 9; ++j) acc9[b][j] = fmaf(wf, cur[j], acc9[b][j]);
        }
    }

    float ss[BB];
#pragma unroll
    for (int b = 0; b < BB; ++b) {
        const float sm = 1.0f + style[b * DD + i];
        float tv = 0.f;
#pragma unroll
        for (int j = 0; j < 9; ++j) {
            acc9[b][j] *= sm;
            tv = fmaf(acc9[b][j], acc9[b][j], tv);
        }
        ss[b] = tv;
    }

    const int wave = i >> 6, lane = i & 63;
#pragma unroll
    for (int b = 0; b < BB; ++b) {
        float tv = ss[b];
#pragma unroll
        for (int off = 32; off > 0; off >>= 1) tv += __shfl_down(tv, off, 64);
        if (lane == 0) red[wave][b] = tv;
    }
    __syncthreads();
    if (i < BB)
        nrm[i] = rsqrtf(red[0][i] + red[1][i] + red[2][i] + red[3][i] + 1e-8f);
    __syncthreads();

    const int ib = i >> 3, e = i & 7;
#pragma unroll
    for (int b = 0; b < BB; ++b) {
        const float nb = nrm[b];
#pragma unroll
        for (int j = 0; j < 9; ++j) {
            const size_t idx = ((((size_t)(b * 9 + j) * 32 + ib) * DD) + o) * 8 + e;
            Ak[idx] = f2bf(acc9[b][j] * nb);
        }
    }
}

// ---------------------------------------------------------------------------
// Kernel B: implicit-GEMM conv, MFMA 16x16x32 bf16.
// grid = 1024 (XCD-swizzled), block = 256 (4 waves, each 32o x 64px fm2/fn4).
// Block tile: 128 o x (1 row x 64 cols). 4 blocks/CU -> 4 waves/SIMD, small
// independent barriers. Staging issued mid-loop (after tap 4), written late.
// ---------------------------------------------------------------------------
#define XROWS 3
#define XCELLS 66
#define XCELLB 80
#define XBUF (XROWS * XCELLS * XCELLB)   // 15840 B

__global__ __launch_bounds__(256, 4) void conv_mfma(
    const ushort* __restrict__ xb,   // (B, 64, 64, D) bf16
    const ushort* __restrict__ Ak,   // (B, 9, 32, 256, 8) bf16
    float* __restrict__ out)         // (B, D, 64, 64) fp32
{
    __shared__ __align__(16) char xs[2 * XBUF];   // 31680 B

    // wgid: xcd = wg&7; rem = wg>>3 (0..127); r = rem&63; Ghi = rem>>6.
    // G = xcd + 8*Ghi -> (ot, b); each XCD hosts 2 (b,ot) groups, all 64 rows.
    const int wg = blockIdx.x;
    const int xcd = wg & 7;
    const int rem = wg >> 3;
    const int r0 = rem & 63;
    const int Ghi = rem >> 6;            // 0..1
    const int G = xcd + 8 * Ghi;         // 0..15
    const int ot = G & 1, b = G >> 1;

    const int o0 = ot * 128;
    const int t = threadIdx.x;
    const int w = t >> 6, l = t & 63;    // w = o-quarter (0..3)
    const int lo = l & 15, lhi = l >> 4;

    // staging: 3 rows * 66 cells * 4 q = 792 16B chunks over 256 threads
    const ushort* sg_ptr[4];
    int sg_lds[4];
    bool sg_ok[4];
    bool sg_act[4];
#pragma unroll
    for (int s = 0; s < 4; ++s) {
        const int idx = t + s * 256;
        sg_act[s] = (s < 3) || (t < 792 - 768);
        const int row = idx / (XCELLS * 4);
        const int rem2 = idx - row * (XCELLS * 4);
        const int cell = rem2 >> 2;
        const int q = rem2 & 3;
        const int gr = r0 - 1 + row;
        const int gc = cell - 1;
        sg_ok[s] = sg_act[s] && ((unsigned)gr < 64u) && ((unsigned)gc < 64u);
        sg_ptr[s] = xb + (((size_t)(b * HH + (gr & 63)) * WW) + (gc & 63)) * DD + q * 8;
        sg_lds[s] = (row * XCELLS + cell) * XCELLB + q * 16;
    }

    f32x4 acc[2][4];
#pragma unroll
    for (int a = 0; a < 2; ++a)
#pragma unroll
        for (int c = 0; c < 4; ++c)
#pragma unroll
            for (int j = 0; j < 4; ++j) acc[a][c][j] = 0.f;

    const int obase = o0 + w * 32 + lo;
    const int bLane = lo * XCELLB + lhi * 16;

    bf16x8 vr[4];
    bf16x8 aF[3][2], bF[2][4];

#define LDA(tp, sl, aB)  do {                                                  \
        const ushort* ap_ = (aB) + (size_t)(tp) * 65536;                       \
        aF[sl][0] = *reinterpret_cast<const bf16x8*>(ap_);                     \
        aF[sl][1] = *reinterpret_cast<const bf16x8*>(ap_ + 128);               \
    } while (0)

#define LDB(tp, sl, bufc)  do {                                                \
        const int dr_ = (tp) / 3, dc_ = (tp) % 3;                              \
        const char* bb_ = (bufc) + (dr_ * XCELLS + dc_) * XCELLB;              \
        bF[sl][0] = *reinterpret_cast<const bf16x8*>(bb_);                     \
        bF[sl][1] = *reinterpret_cast<const bf16x8*>(bb_ + 16 * XCELLB);       \
        bF[sl][2] = *reinterpret_cast<const bf16x8*>(bb_ + 32 * XCELLB);       \
        bF[sl][3] = *reinterpret_cast<const bf16x8*>(bb_ + 48 * XCELLB);       \
    } while (0)

    // prologue: stage chunk 0 into buffer 0
#pragma unroll
    for (int s = 0; s < 4; ++s) {
        if (sg_act[s]) {
            bf16x8 v = {0, 0, 0, 0, 0, 0, 0, 0};
            if (sg_ok[s]) v = *reinterpret_cast<const bf16x8*>(sg_ptr[s]);
            *reinterpret_cast<bf16x8*>(xs + sg_lds[s]) = v;
        }
    }
    __syncthreads();

    for (int kc = 0; kc < 8; ++kc) {
        const int cur = kc & 1;
        const char* bufc = xs + cur * XBUF + bLane;
        const int ib = kc * 4 + lhi;
        const ushort* aLane =
            Ak + ((((size_t)b * 9 * 32) + ib) * DD + obase) * 8;

        LDA(0, 0, aLane);
        LDA(1, 1, aLane);
        LDB(0, 0, bufc);
#pragma unroll
        for (int tap = 0; tap < 9; ++tap) {
            const int as = tap % 3;
            if (tap + 2 <= 8) LDA(tap + 2, (tap + 2) % 3, aLane);
            if (tap < 8) LDB(tap + 1, (tap + 1) & 1, bufc);
            const int bs = tap & 1;
            __builtin_amdgcn_s_setprio(1);
#pragma unroll
            for (int fm = 0; fm < 2; ++fm)
#pragma unroll
                for (int fn = 0; fn < 4; ++fn)
                    acc[fm][fn] = __builtin_amdgcn_mfma_f32_16x16x32_bf16(
                        aF[as][fm], bF[bs][fn], acc[fm][fn], 0, 0, 0);
            __builtin_amdgcn_s_setprio(0);

            // issue next-chunk staging loads mid-loop: taps 0..4's A-waits are
            // clean of the vmcnt FIFO; taps 5..8 cover most of the latency.
            if (tap == 4 && kc < 7) {
                __builtin_amdgcn_sched_barrier(0);
                const int ioff = (kc + 1) * 32;
#pragma unroll
                for (int s = 0; s < 4; ++s) {
                    bf16x8 v = {0, 0, 0, 0, 0, 0, 0, 0};
                    if (sg_ok[s]) v = *reinterpret_cast<const bf16x8*>(sg_ptr[s] + ioff);
                    vr[s] = v;
                }
            }
        }

        // write staged chunk to the other buffer
        if (kc < 7) {
            char* dstb = xs + (cur ^ 1) * XBUF;
#pragma unroll
            for (int s = 0; s < 4; ++s)
                if (sg_act[s]) *reinterpret_cast<bf16x8*>(dstb + sg_lds[s]) = vr[s];
        }
        __syncthreads();
    }
#undef LDA
#undef LDB

    // epilogue: C/D layout col=lane&15 (px), row=(lane>>4)*4+reg (o)
#pragma unroll
    for (int fm = 0; fm < 2; ++fm) {
#pragma unroll
        for (int fn = 0; fn < 4; ++fn) {
            const int oo = o0 + w * 32 + fm * 16 + lhi * 4;
            const int cc = fn * 16 + lo;
            float* op = out + (((size_t)(b * DD + oo) * HH) + r0) * WW + cc;
#pragma unroll
            for (int j = 0; j < 4; ++j) op[(size_t)j * HH * WW] = acc[fm][fn][j];
        }
    }
}

extern "C" void kernel_launch(void* const* d_in, const int* in_sizes, int n_in,
                              void* d_out, int out_size, void* d_ws, size_t ws_size,
                              hipStream_t stream) {
    const float* x            = (const float*)d_in[0];  // (8,256,64,64)
    const float* bank_request = (const float*)d_in[1];  // (8,16)
    const float* style        = (const float*)d_in[2];  // (8,1,256,1,1)
    const float* bank_weight  = (const float*)d_in[3];  // (16,256,256,3,3)
    float* out = (float*)d_out;                         // (8,256,64,64)

    ushort* Ak = (ushort*)d_ws;                         // 8*9*32*256*8 elems
    ushort* xb = Ak + (size_t)8 * 9 * 32 * 256 * 8;     // 8*64*64*256 elems

    prep_fused<<<dim3(768), 256, 0, stream>>>(x, bank_request, style, bank_weight, xb, Ak);
    conv_mfma<<<dim3(1024), 256, 0, stream>>>(xb, Ak, out);
}